// Round 8
// baseline (786.805 us; speedup 1.0000x reference)
//
#include <hip/hip_runtime.h>
#include <hip/hip_cooperative_groups.h>
#include <math.h>

namespace cg = cooperative_groups;

#define NN   20000
#define EE   320000
#define ETOT 340000
#define FIN  128
#define HH   4
#define CC   64
#define HC   256
#define GG   64
#define BN_EPS 1e-5f
#define S1   384   // Bcat1 stride: 256 (W1 perm) + 64 (Wskip) + 8 (es/ed) + 56 pad
#define S2   320   // Bcat2 stride: 256 (W2 perm) + 8 (es/ed) + 56 pad
#define STATB 128  // blocks producing BN partials

__device__ __forceinline__ unsigned short f2bf(float f) {
    unsigned u = __float_as_uint(f);
    unsigned r = (u + 0x7FFF + ((u >> 16) & 1)) >> 16;   // RNE
    return (unsigned short)r;
}
__device__ __forceinline__ float bf2f(unsigned short u) {
    return __uint_as_float((unsigned)u << 16);
}
__device__ __forceinline__ float gelu_exact(float v) {
    return 0.5f * v * (1.f + erff(v * 0.70710678118654752f));
}

// ================= pre: zero + gbound + Bcat build + CSR (coop, 4 syncs) ==========
__global__ __launch_bounds__(256) void pre_kernel(
        const int* __restrict__ bidx, int* __restrict__ gstart,
        const float* __restrict__ W1, const float* __restrict__ Wskip,
        const float* __restrict__ W2,
        const float* __restrict__ as1, const float* __restrict__ ad1,
        const float* __restrict__ as2, const float* __restrict__ ad2,
        float* __restrict__ Bcat1, float* __restrict__ Bcat2,
        const int* __restrict__ ei, int* __restrict__ deg, int* __restrict__ off,
        int* __restrict__ part, int* __restrict__ cursor, int* __restrict__ csr) {
    cg::grid_group grid = cg::this_grid();
    __shared__ int buf[256];
    __shared__ int buf2[128];
    int t = threadIdx.x, b = blockIdx.x;
    int gid = b * 256 + t;
    const int G = gridDim.x * 256;

    // ---- phase 0: zero counters, graph boundaries, Bcat1/Bcat2 construction ----
    // NOTE: pad-zero loops must NOT overlap the es/ed dot-product columns
    // (Bcat1 cols 320..327, Bcat2 cols 256..263) — same-phase write race (R7 bug).
    for (int i = gid; i < 2 * NN; i += G) {
        if (i < NN) deg[i] = 0; else cursor[i - NN] = 0;
    }
    for (int i = gid; i < NN; i += G) {
        int cur = bidx[i];
        if (i == 0) { for (int g = 0; g <= cur; ++g) gstart[g] = 0; }
        else { int prev = bidx[i - 1]; for (int g = prev + 1; g <= cur; ++g) gstart[g] = i; }
        if (i == NN - 1) { for (int g = cur + 1; g <= GG; ++g) gstart[g] = NN; }
    }
    for (int i = gid; i < FIN * 256; i += G) {        // W1 permuted -> cols 0..255
        int col = i & 255, f = i >> 8;
        int h = col & 3, c = col >> 2;
        Bcat1[f * S1 + col] = W1[f * 256 + h * 64 + c];
    }
    for (int i = gid; i < FIN * 64; i += G) {         // Wskip -> cols 256..319
        int f = i >> 6, c = i & 63;
        Bcat1[f * S1 + 256 + c] = Wskip[f * 64 + c];
    }
    for (int i = gid; i < FIN * 64; i += G) {         // zero pad cols 328..383 ONLY
        int f = i >> 6, c = i & 63;
        if (c >= 8) Bcat1[f * S1 + 320 + c] = 0.f;
    }
    for (int i = gid; i < CC * 256; i += G) {         // W2 permuted -> cols 0..255
        int col = i & 255, f = i >> 8;
        int h = col & 3, c = col >> 2;
        Bcat2[f * S2 + col] = W2[f * 256 + h * 64 + c];
    }
    for (int i = gid; i < CC * 64; i += G) {          // zero pad cols 264..319 ONLY
        int f = i >> 6, c = i & 63;
        if (c >= 8) Bcat2[f * S2 + 256 + c] = 0.f;
    }
    for (int i = gid; i < FIN * 8; i += G) {          // es/ed weights -> cols 320..327
        int f = i >> 3, k = i & 7, h = k & 3;
        const float* av = (k < 4 ? as1 : ad1) + h * 64;
        const float* wr = W1 + f * 256 + h * 64;
        float s = 0.f;
        #pragma unroll 8
        for (int c = 0; c < 64; ++c) s += wr[c] * av[c];
        Bcat1[f * S1 + 320 + k] = s;
    }
    for (int i = gid; i < CC * 8; i += G) {           // es/ed weights -> cols 256..263
        int f = i >> 3, k = i & 7, h = k & 3;
        const float* av = (k < 4 ? as2 : ad2) + h * 64;
        const float* wr = W2 + f * 256 + h * 64;
        float s = 0.f;
        #pragma unroll 8
        for (int c = 0; c < 64; ++c) s += wr[c] * av[c];
        Bcat2[f * S2 + 256 + k] = s;
    }
    grid.sync();
    // ---- phase 1: degree count ----
    for (int i = gid; i < ETOT; i += G) {
        int d = (i < EE) ? ei[EE + i] : (i - EE);
        atomicAdd(&deg[d], 1);
    }
    grid.sync();
    // ---- phase 2: block-local exclusive scan (blocks 0..78) ----
    if (b < 79) {
        int i = b * 256 + t;
        int v = (i < NN) ? deg[i] : 0;
        buf[t] = v; __syncthreads();
        for (int s = 1; s < 256; s <<= 1) {
            int x = (t >= s) ? buf[t - s] : 0;
            __syncthreads(); buf[t] += x; __syncthreads();
        }
        if (i < NN) off[i] = buf[t] - v;
        if (t == 255) part[b] = buf[t];
    }
    grid.sync();
    // ---- phase 3: add scanned block partials ----
    if (b < 79) {
        if (t < 128) buf2[t] = (t < 79) ? part[t] : 0;
        __syncthreads();
        for (int s = 1; s < 128; s <<= 1) {
            int x = (t >= s && t < 128) ? buf2[t - s] : 0;
            __syncthreads(); if (t < 128) buf2[t] += x; __syncthreads();
        }
        int prefix = (b == 0) ? 0 : buf2[b - 1];
        int i = b * 256 + t;
        if (i < NN) off[i] += prefix;
        if (i == 0) off[NN] = ETOT;
    }
    grid.sync();
    // ---- phase 4: CSR fill ----
    for (int i = gid; i < ETOT; i += G) {
        int s, d;
        if (i < EE) { s = ei[i]; d = ei[EE + i]; } else { s = i - EE; d = i - EE; }
        int pos = atomicAdd(&cursor[d], 1);
        csr[off[d] + pos] = s;
    }
}

// ================= fused GEMM: h4b (bf16) + optional skip (fp32) + es/ed ==========
// C = A[M,K] @ Bcat[K,S]; col tiles: [0,4): bf16 h4b; skip_tile: fp32 skip;
// esed_tile: cols 0..3 -> es4, cols 4..7 -> ed4.
__global__ __launch_bounds__(256) void gemm_fused(const float* __restrict__ A,
        const float* __restrict__ B, int M, int K, int S,
        unsigned short* __restrict__ h4b, float* __restrict__ skipO,
        float4* __restrict__ es4, float4* __restrict__ ed4,
        int skip_tile, int esed_tile) {
    __shared__ float sAT[32][68];
    __shared__ float sB[32][68];
    int t = threadIdx.x;
    int tile = blockIdx.x;
    int col0 = tile * 64;
    int row0 = blockIdx.y * 64;
    int tx = t & 15, ty = t >> 4;
    float acc[4][4] = {};
    for (int k0 = 0; k0 < K; k0 += 32) {
        #pragma unroll
        for (int i = 0; i < 2; ++i) {
            int e = t + i * 256;
            int r = e >> 3, c4 = e & 7;
            int gr = row0 + r;
            float4 v = make_float4(0.f, 0.f, 0.f, 0.f);
            if (gr < M) v = *(const float4*)&A[(size_t)gr * K + k0 + c4 * 4];
            sAT[c4 * 4 + 0][r] = v.x;
            sAT[c4 * 4 + 1][r] = v.y;
            sAT[c4 * 4 + 2][r] = v.z;
            sAT[c4 * 4 + 3][r] = v.w;
        }
        #pragma unroll
        for (int i = 0; i < 2; ++i) {
            int e = t + i * 256;
            int r = e >> 4, c4 = e & 15;
            float4 v = *(const float4*)&B[(size_t)(k0 + r) * S + col0 + c4 * 4];
            *(float4*)&sB[r][c4 * 4] = v;
        }
        __syncthreads();
        #pragma unroll
        for (int kk = 0; kk < 32; ++kk) {
            float4 a = *(const float4*)&sAT[kk][ty * 4];
            float4 b = *(const float4*)&sB[kk][tx * 4];
            acc[0][0] += a.x * b.x; acc[0][1] += a.x * b.y; acc[0][2] += a.x * b.z; acc[0][3] += a.x * b.w;
            acc[1][0] += a.y * b.x; acc[1][1] += a.y * b.y; acc[1][2] += a.y * b.z; acc[1][3] += a.y * b.w;
            acc[2][0] += a.z * b.x; acc[2][1] += a.z * b.y; acc[2][2] += a.z * b.z; acc[2][3] += a.z * b.w;
            acc[3][0] += a.w * b.x; acc[3][1] += a.w * b.y; acc[3][2] += a.w * b.z; acc[3][3] += a.w * b.w;
        }
        __syncthreads();
    }
    if (tile < 4) {
        #pragma unroll
        for (int j = 0; j < 4; ++j) {
            int gr = row0 + ty * 4 + j;
            if (gr < M) {
                ushort4 v;
                v.x = f2bf(acc[j][0]); v.y = f2bf(acc[j][1]);
                v.z = f2bf(acc[j][2]); v.w = f2bf(acc[j][3]);
                *(ushort4*)&h4b[(size_t)gr * HC + col0 + tx * 4] = v;
            }
        }
    } else if (tile == skip_tile) {
        #pragma unroll
        for (int j = 0; j < 4; ++j) {
            int gr = row0 + ty * 4 + j;
            if (gr < M) {
                float4 v = make_float4(acc[j][0], acc[j][1], acc[j][2], acc[j][3]);
                *(float4*)&skipO[(size_t)gr * CC + tx * 4] = v;
            }
        }
    } else if (tile == esed_tile) {
        if (tx < 2) {
            #pragma unroll
            for (int j = 0; j < 4; ++j) {
                int gr = row0 + ty * 4 + j;
                if (gr < M) {
                    float4 v = make_float4(acc[j][0], acc[j][1], acc[j][2], acc[j][3]);
                    if (tx == 0) es4[gr] = v; else ed4[gr] = v;
                }
            }
        }
    }
}

// ================= per-destination GAT aggregation (bf16 gather) ===================
__device__ __forceinline__ void edge_acc(const float4 esv, const ushort4 hv,
        const float4 edn, float4& acc, float4& ssum) {
    float e0 = esv.x + edn.x; e0 = fmaxf(e0, 0.2f * e0); float w0 = __expf(e0);
    float e1 = esv.y + edn.y; e1 = fmaxf(e1, 0.2f * e1); float w1 = __expf(e1);
    float e2 = esv.z + edn.z; e2 = fmaxf(e2, 0.2f * e2); float w2 = __expf(e2);
    float e3 = esv.w + edn.w; e3 = fmaxf(e3, 0.2f * e3); float w3 = __expf(e3);
    acc.x += w0 * bf2f(hv.x); ssum.x += w0;
    acc.y += w1 * bf2f(hv.y); ssum.y += w1;
    acc.z += w2 * bf2f(hv.z); ssum.z += w2;
    acc.w += w3 * bf2f(hv.w); ssum.w += w3;
}

__global__ __launch_bounds__(256) void aggr_kernel(const unsigned short* __restrict__ h4b,
        const float4* __restrict__ es4, const float4* __restrict__ ed4,
        const int* __restrict__ off, const int* __restrict__ csr_src,
        const float* __restrict__ bias, float* __restrict__ out) {
    int n = blockIdx.x * 4 + (threadIdx.x >> 6);
    if (n >= NN) return;
    int lane = threadIdx.x & 63;
    float4 edn = ed4[n];
    float4 acc = make_float4(0.f, 0.f, 0.f, 0.f);
    float4 ssum = make_float4(0.f, 0.f, 0.f, 0.f);
    int beg = off[n], end = off[n + 1];
    int j = beg;
    for (; j + 4 <= end; j += 4) {
        int s0 = csr_src[j + 0];
        int s1 = csr_src[j + 1];
        int s2 = csr_src[j + 2];
        int s3 = csr_src[j + 3];
        float4 E0 = es4[s0];
        float4 E1 = es4[s1];
        float4 E2 = es4[s2];
        float4 E3 = es4[s3];
        ushort4 v0 = *(const ushort4*)&h4b[(size_t)s0 * HC + lane * 4];
        ushort4 v1 = *(const ushort4*)&h4b[(size_t)s1 * HC + lane * 4];
        ushort4 v2 = *(const ushort4*)&h4b[(size_t)s2 * HC + lane * 4];
        ushort4 v3 = *(const ushort4*)&h4b[(size_t)s3 * HC + lane * 4];
        edge_acc(E0, v0, edn, acc, ssum);
        edge_acc(E1, v1, edn, acc, ssum);
        edge_acc(E2, v2, edn, acc, ssum);
        edge_acc(E3, v3, edn, acc, ssum);
    }
    for (; j < end; ++j) {
        int s = csr_src[j];
        float4 E = es4[s];
        ushort4 v = *(const ushort4*)&h4b[(size_t)s * HC + lane * 4];
        edge_acc(E, v, edn, acc, ssum);
    }
    float val = 0.25f * (acc.x / (ssum.x + 1e-16f) + acc.y / (ssum.y + 1e-16f) +
                         acc.z / (ssum.z + 1e-16f) + acc.w / (ssum.w + 1e-16f)) + bias[lane];
    out[n * CC + lane] = val;
}

// ================= BN layer1: stats (2-stage) + apply (coop, 2 syncs) ==============
__global__ __launch_bounds__(256) void bn1_kernel(const float* __restrict__ gout,
        float* __restrict__ pbuf, float* __restrict__ stats,
        const float* __restrict__ g, const float* __restrict__ be,
        const float* __restrict__ skip, const float* __restrict__ bskip,
        float* __restrict__ outm) {
    cg::grid_group grid = cg::this_grid();
    __shared__ float ls[4][64], lq[4][64];
    int t = threadIdx.x, b = blockIdx.x;
    int gid = b * 256 + t;
    const int G = gridDim.x * 256;
    int ch = t & 63, slice = t >> 6;
    if (b < STATB) {
        float s = 0.f, q = 0.f;
        for (int n = b * 4 + slice; n < NN; n += STATB * 4) {
            float v = gout[n * CC + ch];
            s += v; q += v * v;
        }
        ls[slice][ch] = s; lq[slice][ch] = q;
        __syncthreads();
        if (slice == 0) {
            s = ls[0][ch] + ls[1][ch] + ls[2][ch] + ls[3][ch];
            q = lq[0][ch] + lq[1][ch] + lq[2][ch] + lq[3][ch];
            pbuf[b * 128 + ch] = s;
            pbuf[b * 128 + 64 + ch] = q;
        }
    }
    grid.sync();
    if (b == 0 && t < 128) {
        float s = 0.f;
        for (int bb = 0; bb < STATB; bb += 4)
            s += pbuf[bb * 128 + t] + pbuf[(bb + 1) * 128 + t]
               + pbuf[(bb + 2) * 128 + t] + pbuf[(bb + 3) * 128 + t];
        stats[t] = s;
    }
    grid.sync();
    for (int i = gid; i < NN * CC; i += G) {
        int c = i & 63;
        float mu  = stats[c] * (1.f / NN);
        float var = stats[CC + c] * (1.f / NN) - mu * mu;
        float inv = rsqrtf(var + BN_EPS);
        float v = (gout[i] - mu) * inv * g[c] + be[c] + skip[i] + bskip[c];
        outm[i] = gelu_exact(v);
    }
}

// ================= BN layer2 + residual + pool (coop, 3 syncs) =====================
__global__ __launch_bounds__(256) void bn2_kernel(const float* __restrict__ gout,
        float* __restrict__ pbuf, float* __restrict__ stats,
        const float* __restrict__ g, const float* __restrict__ be,
        const float* __restrict__ resid, float* __restrict__ h2,
        const int* __restrict__ gstart, float* __restrict__ out) {
    cg::grid_group grid = cg::this_grid();
    __shared__ float ls[4][64], lq[4][64];
    __shared__ float4 sdata[16][17];
    int t = threadIdx.x, b = blockIdx.x;
    int gid = b * 256 + t;
    const int G = gridDim.x * 256;
    int ch = t & 63, slice = t >> 6;
    if (b < STATB) {
        float s = 0.f, q = 0.f;
        for (int n = b * 4 + slice; n < NN; n += STATB * 4) {
            float v = gout[n * CC + ch];
            s += v; q += v * v;
        }
        ls[slice][ch] = s; lq[slice][ch] = q;
        __syncthreads();
        if (slice == 0) {
            s = ls[0][ch] + ls[1][ch] + ls[2][ch] + ls[3][ch];
            q = lq[0][ch] + lq[1][ch] + lq[2][ch] + lq[3][ch];
            pbuf[b * 128 + ch] = s;
            pbuf[b * 128 + 64 + ch] = q;
        }
    }
    grid.sync();
    if (b == 0 && t < 128) {
        float s = 0.f;
        for (int bb = 0; bb < STATB; bb += 4)
            s += pbuf[bb * 128 + t] + pbuf[(bb + 1) * 128 + t]
               + pbuf[(bb + 2) * 128 + t] + pbuf[(bb + 3) * 128 + t];
        stats[t] = s;
    }
    grid.sync();
    for (int i = gid; i < NN * CC; i += G) {
        int c = i & 63;
        float mu  = stats[c] * (1.f / NN);
        float var = stats[CC + c] * (1.f / NN) - mu * mu;
        float inv = rsqrtf(var + BN_EPS);
        float v = (gout[i] - mu) * inv * g[c] + be[c] + resid[i];
        h2[i] = gelu_exact(v);
    }
    grid.sync();
    // pool: blocks 0..63, one per graph; 16 node-slices x 16 float4-channels
    if (b < GG) {
        int c4 = t & 15, sl = t >> 4;
        int start = gstart[b], end = gstart[b + 1];
        float4 acc = make_float4(0.f, 0.f, 0.f, 0.f);
        for (int n = start + sl; n < end; n += 16) {
            float4 v = *(const float4*)&h2[(size_t)n * CC + c4 * 4];
            acc.x += v.x; acc.y += v.y; acc.z += v.z; acc.w += v.w;
        }
        sdata[sl][c4] = acc;
        __syncthreads();
        #pragma unroll
        for (int s = 8; s >= 1; s >>= 1) {
            if (sl < s) {
                float4 o = sdata[sl + s][c4];
                acc.x += o.x; acc.y += o.y; acc.z += o.z; acc.w += o.w;
                sdata[sl][c4] = acc;
            }
            __syncthreads();
        }
        if (sl == 0) {
            int cnt = end - start;
            float inv = 1.f / (float)((cnt > 0) ? cnt : 1);
            *(float4*)&out[b * CC + c4 * 4] =
                make_float4(acc.x * inv, acc.y * inv, acc.z * inv, acc.w * inv);
        }
    }
}

extern "C" void kernel_launch(void* const* d_in, const int* in_sizes, int n_in,
                              void* d_out, int out_size, void* d_ws, size_t ws_size,
                              hipStream_t stream) {
    const float* x      = (const float*)d_in[0];
    const float* W1     = (const float*)d_in[1];
    const float* a_src1 = (const float*)d_in[2];
    const float* a_dst1 = (const float*)d_in[3];
    const float* b1     = (const float*)d_in[4];
    const float* Wskip  = (const float*)d_in[5];
    const float* bskip  = (const float*)d_in[6];
    const float* g1     = (const float*)d_in[7];
    const float* be1    = (const float*)d_in[8];
    const float* W2     = (const float*)d_in[9];
    const float* a_src2 = (const float*)d_in[10];
    const float* a_dst2 = (const float*)d_in[11];
    const float* b2     = (const float*)d_in[12];
    const float* g2     = (const float*)d_in[13];
    const float* be2    = (const float*)d_in[14];
    const int*   ei     = (const int*)d_in[15];
    const int*   bidx   = (const int*)d_in[16];
    float* out = (float*)d_out;

    char* w = (char*)d_ws;
    size_t o = 0;
    auto alloc = [&](size_t bytes) -> void* {
        void* p = w + o;
        o = (o + bytes + 255) & ~(size_t)255;
        return p;
    };

    unsigned short* h4b = (unsigned short*)alloc((size_t)NN * HC * 2);  // bf16 [N][C][H]
    float4* es4 = (float4*)alloc((size_t)NN * 16);
    float4* ed4 = (float4*)alloc((size_t)NN * 16);
    float* skip = (float*)alloc((size_t)NN * CC * 4);
    float* gout = (float*)alloc((size_t)NN * CC * 4);
    float* hmid = (float*)alloc((size_t)NN * CC * 4);
    float* h2   = (float*)alloc((size_t)NN * CC * 4);
    float* Bcat1 = (float*)alloc((size_t)FIN * S1 * 4);
    float* Bcat2 = (float*)alloc((size_t)CC * S2 * 4);
    float* pbuf  = (float*)alloc((size_t)STATB * 128 * 4);
    int* off    = (int*)alloc((size_t)(NN + 1) * 4);
    int* csr    = (int*)alloc((size_t)ETOT * 4);
    int* gstart = (int*)alloc((size_t)(GG + 1) * 4);
    int* deg    = (int*)alloc((size_t)NN * 4);
    int* cursor = (int*)alloc((size_t)NN * 4);
    int* part   = (int*)alloc(128 * 4);
    float* stats1 = (float*)alloc(128 * 4);
    float* stats2 = (float*)alloc(128 * 4);

    // ---- launch 1: pre (cooperative) ----
    {
        void* args[] = { (void*)&bidx, (void*)&gstart, (void*)&W1, (void*)&Wskip,
                         (void*)&W2, (void*)&a_src1, (void*)&a_dst1, (void*)&a_src2,
                         (void*)&a_dst2, (void*)&Bcat1, (void*)&Bcat2, (void*)&ei,
                         (void*)&deg, (void*)&off, (void*)&part, (void*)&cursor,
                         (void*)&csr };
        hipLaunchCooperativeKernel((void*)pre_kernel, dim3(512), dim3(256),
                                   args, 0, stream);
    }

    int nodeblk = (NN + 3) / 4;

    // ---- launch 2: layer-1 fused GEMM (h4b + skip + es/ed) ----
    gemm_fused<<<dim3(6, 313), 256, 0, stream>>>(x, Bcat1, NN, FIN, S1,
            h4b, skip, es4, ed4, 4, 5);
    // ---- launch 3: layer-1 aggregation ----
    aggr_kernel<<<nodeblk, 256, 0, stream>>>(h4b, es4, ed4, off, csr, b1, gout);
    // ---- launch 4: BN1 + skip + GELU (cooperative) ----
    {
        void* args[] = { (void*)&gout, (void*)&pbuf, (void*)&stats1, (void*)&g1,
                         (void*)&be1, (void*)&skip, (void*)&bskip, (void*)&hmid };
        hipLaunchCooperativeKernel((void*)bn1_kernel, dim3(512), dim3(256),
                                   args, 0, stream);
    }
    // ---- launch 5: layer-2 fused GEMM (h4b + es/ed) ----
    gemm_fused<<<dim3(5, 313), 256, 0, stream>>>(hmid, Bcat2, NN, CC, S2,
            h4b, (float*)nullptr, es4, ed4, -1, 4);
    // ---- launch 6: layer-2 aggregation ----
    aggr_kernel<<<nodeblk, 256, 0, stream>>>(h4b, es4, ed4, off, csr, b2, gout);
    // ---- launch 7: BN2 + residual + GELU + pool (cooperative) ----
    {
        void* args[] = { (void*)&gout, (void*)&pbuf, (void*)&stats2, (void*)&g2,
                         (void*)&be2, (void*)&hmid, (void*)&h2, (void*)&gstart,
                         (void*)&out };
        hipLaunchCooperativeKernel((void*)bn2_kernel, dim3(512), dim3(256),
                                   args, 0, stream);
    }
}

// Round 9
// 283.396 us; speedup vs baseline: 2.7763x; 2.7763x over previous
//
#include <hip/hip_runtime.h>
#include <math.h>

#define NN   20000
#define EE   320000
#define ETOT 340000
#define FIN  128
#define HH   4
#define CC   64
#define HC   256
#define GG   64
#define BN_EPS 1e-5f
#define S1   384   // Bcat1 stride: 256 (W1 perm) + 64 (Wskip) + 8 (es/ed) + 56 pad
#define S2   320   // Bcat2 stride: 256 (W2 perm) + 8 (es/ed) + 56 pad

__device__ __forceinline__ unsigned short f2bf(float f) {
    unsigned u = __float_as_uint(f);
    unsigned r = (u + 0x7FFF + ((u >> 16) & 1)) >> 16;   // RNE
    return (unsigned short)r;
}
__device__ __forceinline__ float bf2f(unsigned short u) {
    return __uint_as_float((unsigned)u << 16);
}
__device__ __forceinline__ float gelu_exact(float v) {
    return 0.5f * v * (1.f + erff(v * 0.70710678118654752f));
}

// ====== pre1: block-partitioned  gbound | Bcat1 | Bcat2 | degree count ============
// blocks [0,79): gbound;  [79,271): Bcat1 (192);  [271,351): Bcat2 (80);
// [351,1680): degree count (1329).  deg/cursor zeroed by prior memset.
__global__ __launch_bounds__(256) void pre1_kernel(
        const int* __restrict__ bidx, int* __restrict__ gstart,
        const float* __restrict__ W1, const float* __restrict__ Wskip,
        const float* __restrict__ W2,
        const float* __restrict__ as1, const float* __restrict__ ad1,
        const float* __restrict__ as2, const float* __restrict__ ad2,
        float* __restrict__ Bcat1, float* __restrict__ Bcat2,
        const int* __restrict__ ei, int* __restrict__ deg) {
    int b = blockIdx.x, t = threadIdx.x;
    if (b < 79) {
        int i = b * 256 + t;
        if (i >= NN) return;
        int cur = bidx[i];
        if (i == 0) { for (int g = 0; g <= cur; ++g) gstart[g] = 0; }
        else { int prev = bidx[i - 1]; for (int g = prev + 1; g <= cur; ++g) gstart[g] = i; }
        if (i == NN - 1) { for (int g = cur + 1; g <= GG; ++g) gstart[g] = NN; }
    } else if (b < 271) {
        int i = (b - 79) * 256 + t;          // i < FIN*S1 = 49152
        int f = i / S1, col = i - f * S1;
        float v;
        if (col < 256) {
            int h = col & 3, c = col >> 2;
            v = W1[f * 256 + h * 64 + c];
        } else if (col < 320) {
            v = Wskip[f * 64 + (col - 256)];
        } else if (col < 328) {
            int k = col - 320, h = k & 3;
            const float* av = (k < 4 ? as1 : ad1) + h * 64;
            const float* wr = W1 + f * 256 + h * 64;
            float s = 0.f;
            #pragma unroll 8
            for (int c = 0; c < 64; ++c) s += wr[c] * av[c];
            v = s;
        } else v = 0.f;
        Bcat1[i] = v;
    } else if (b < 351) {
        int i = (b - 271) * 256 + t;         // i < CC*S2 = 20480
        int f = i / S2, col = i - f * S2;
        float v;
        if (col < 256) {
            int h = col & 3, c = col >> 2;
            v = W2[f * 256 + h * 64 + c];
        } else if (col < 264) {
            int k = col - 256, h = k & 3;
            const float* av = (k < 4 ? as2 : ad2) + h * 64;
            const float* wr = W2 + f * 256 + h * 64;
            float s = 0.f;
            #pragma unroll 8
            for (int c = 0; c < 64; ++c) s += wr[c] * av[c];
            v = s;
        } else v = 0.f;
        Bcat2[i] = v;
    } else {
        int i = (b - 351) * 256 + t;
        if (i >= ETOT) return;
        int d = (i < EE) ? ei[EE + i] : (i - EE);
        atomicAdd(&deg[d], 1);
    }
}

// ---------------- CSR scan chain ----------------
__global__ __launch_bounds__(256) void scan1(const int* __restrict__ deg,
        int* __restrict__ off, int* __restrict__ part) {
    __shared__ int buf[256];
    int b = blockIdx.x, t = threadIdx.x;
    int i = b * 256 + t;
    int v = (i < NN) ? deg[i] : 0;
    buf[t] = v; __syncthreads();
    for (int s = 1; s < 256; s <<= 1) {
        int x = (t >= s) ? buf[t - s] : 0;
        __syncthreads(); buf[t] += x; __syncthreads();
    }
    if (i < NN) off[i] = buf[t] - v;
    if (t == 255) part[b] = buf[t];
}

__global__ __launch_bounds__(256) void scan23(int* __restrict__ off,
        const int* __restrict__ part) {
    __shared__ int buf[128];
    int t = threadIdx.x, b = blockIdx.x;
    if (t < 128) buf[t] = (t < (int)gridDim.x) ? part[t] : 0;
    __syncthreads();
    for (int s = 1; s < 128; s <<= 1) {
        int x = (t >= s && t < 128) ? buf[t - s] : 0;
        __syncthreads(); if (t < 128) buf[t] += x; __syncthreads();
    }
    int prefix = (b == 0) ? 0 : buf[b - 1];
    int i = b * 256 + t;
    if (i < NN) off[i] += prefix;
    if (i == 0) off[NN] = ETOT;
}

__global__ void fill_kernel(const int* __restrict__ ei, const int* __restrict__ off,
        int* __restrict__ cursor, int* __restrict__ csr_src) {
    int i = blockIdx.x * 256 + threadIdx.x;
    if (i >= ETOT) return;
    int s, d;
    if (i < EE) { s = ei[i]; d = ei[EE + i]; } else { s = i - EE; d = i - EE; }
    int pos = atomicAdd(&cursor[d], 1);
    csr_src[off[d] + pos] = s;
}

// ================= fused GEMM: h4b (bf16) + optional skip (fp32) + es/ed ==========
__global__ __launch_bounds__(256) void gemm_fused(const float* __restrict__ A,
        const float* __restrict__ B, int M, int K, int S,
        unsigned short* __restrict__ h4b, float* __restrict__ skipO,
        float4* __restrict__ es4, float4* __restrict__ ed4,
        int skip_tile, int esed_tile) {
    __shared__ float sAT[32][68];
    __shared__ float sB[32][68];
    int t = threadIdx.x;
    int tile = blockIdx.x;
    int col0 = tile * 64;
    int row0 = blockIdx.y * 64;
    int tx = t & 15, ty = t >> 4;
    float acc[4][4] = {};
    for (int k0 = 0; k0 < K; k0 += 32) {
        #pragma unroll
        for (int i = 0; i < 2; ++i) {
            int e = t + i * 256;
            int r = e >> 3, c4 = e & 7;
            int gr = row0 + r;
            float4 v = make_float4(0.f, 0.f, 0.f, 0.f);
            if (gr < M) v = *(const float4*)&A[(size_t)gr * K + k0 + c4 * 4];
            sAT[c4 * 4 + 0][r] = v.x;
            sAT[c4 * 4 + 1][r] = v.y;
            sAT[c4 * 4 + 2][r] = v.z;
            sAT[c4 * 4 + 3][r] = v.w;
        }
        #pragma unroll
        for (int i = 0; i < 2; ++i) {
            int e = t + i * 256;
            int r = e >> 4, c4 = e & 15;
            float4 v = *(const float4*)&B[(size_t)(k0 + r) * S + col0 + c4 * 4];
            *(float4*)&sB[r][c4 * 4] = v;
        }
        __syncthreads();
        #pragma unroll
        for (int kk = 0; kk < 32; ++kk) {
            float4 a = *(const float4*)&sAT[kk][ty * 4];
            float4 b = *(const float4*)&sB[kk][tx * 4];
            acc[0][0] += a.x * b.x; acc[0][1] += a.x * b.y; acc[0][2] += a.x * b.z; acc[0][3] += a.x * b.w;
            acc[1][0] += a.y * b.x; acc[1][1] += a.y * b.y; acc[1][2] += a.y * b.z; acc[1][3] += a.y * b.w;
            acc[2][0] += a.z * b.x; acc[2][1] += a.z * b.y; acc[2][2] += a.z * b.z; acc[2][3] += a.z * b.w;
            acc[3][0] += a.w * b.x; acc[3][1] += a.w * b.y; acc[3][2] += a.w * b.z; acc[3][3] += a.w * b.w;
        }
        __syncthreads();
    }
    if (tile < 4) {
        #pragma unroll
        for (int j = 0; j < 4; ++j) {
            int gr = row0 + ty * 4 + j;
            if (gr < M) {
                ushort4 v;
                v.x = f2bf(acc[j][0]); v.y = f2bf(acc[j][1]);
                v.z = f2bf(acc[j][2]); v.w = f2bf(acc[j][3]);
                *(ushort4*)&h4b[(size_t)gr * HC + col0 + tx * 4] = v;
            }
        }
    } else if (tile == skip_tile) {
        #pragma unroll
        for (int j = 0; j < 4; ++j) {
            int gr = row0 + ty * 4 + j;
            if (gr < M) {
                float4 v = make_float4(acc[j][0], acc[j][1], acc[j][2], acc[j][3]);
                *(float4*)&skipO[(size_t)gr * CC + tx * 4] = v;
            }
        }
    } else if (tile == esed_tile) {
        if (tx < 2) {
            #pragma unroll
            for (int j = 0; j < 4; ++j) {
                int gr = row0 + ty * 4 + j;
                if (gr < M) {
                    float4 v = make_float4(acc[j][0], acc[j][1], acc[j][2], acc[j][3]);
                    if (tx == 0) es4[gr] = v; else ed4[gr] = v;
                }
            }
        }
    }
}

// ================= per-destination GAT aggregation (bf16 gather) ===================
__device__ __forceinline__ void edge_acc(const float4 esv, const ushort4 hv,
        const float4 edn, float4& acc, float4& ssum) {
    float e0 = esv.x + edn.x; e0 = fmaxf(e0, 0.2f * e0); float w0 = __expf(e0);
    float e1 = esv.y + edn.y; e1 = fmaxf(e1, 0.2f * e1); float w1 = __expf(e1);
    float e2 = esv.z + edn.z; e2 = fmaxf(e2, 0.2f * e2); float w2 = __expf(e2);
    float e3 = esv.w + edn.w; e3 = fmaxf(e3, 0.2f * e3); float w3 = __expf(e3);
    acc.x += w0 * bf2f(hv.x); ssum.x += w0;
    acc.y += w1 * bf2f(hv.y); ssum.y += w1;
    acc.z += w2 * bf2f(hv.z); ssum.z += w2;
    acc.w += w3 * bf2f(hv.w); ssum.w += w3;
}

__global__ __launch_bounds__(256) void aggr_kernel(const unsigned short* __restrict__ h4b,
        const float4* __restrict__ es4, const float4* __restrict__ ed4,
        const int* __restrict__ off, const int* __restrict__ csr_src,
        const float* __restrict__ bias, float* __restrict__ out) {
    int n = blockIdx.x * 4 + (threadIdx.x >> 6);
    if (n >= NN) return;
    int lane = threadIdx.x & 63;
    float4 edn = ed4[n];
    float4 acc = make_float4(0.f, 0.f, 0.f, 0.f);
    float4 ssum = make_float4(0.f, 0.f, 0.f, 0.f);
    int beg = off[n], end = off[n + 1];
    int j = beg;
    for (; j + 4 <= end; j += 4) {
        int s0 = csr_src[j + 0];
        int s1 = csr_src[j + 1];
        int s2 = csr_src[j + 2];
        int s3 = csr_src[j + 3];
        float4 E0 = es4[s0];
        float4 E1 = es4[s1];
        float4 E2 = es4[s2];
        float4 E3 = es4[s3];
        ushort4 v0 = *(const ushort4*)&h4b[(size_t)s0 * HC + lane * 4];
        ushort4 v1 = *(const ushort4*)&h4b[(size_t)s1 * HC + lane * 4];
        ushort4 v2 = *(const ushort4*)&h4b[(size_t)s2 * HC + lane * 4];
        ushort4 v3 = *(const ushort4*)&h4b[(size_t)s3 * HC + lane * 4];
        edge_acc(E0, v0, edn, acc, ssum);
        edge_acc(E1, v1, edn, acc, ssum);
        edge_acc(E2, v2, edn, acc, ssum);
        edge_acc(E3, v3, edn, acc, ssum);
    }
    for (; j < end; ++j) {
        int s = csr_src[j];
        float4 E = es4[s];
        ushort4 v = *(const ushort4*)&h4b[(size_t)s * HC + lane * 4];
        edge_acc(E, v, edn, acc, ssum);
    }
    float val = 0.25f * (acc.x / (ssum.x + 1e-16f) + acc.y / (ssum.y + 1e-16f) +
                         acc.z / (ssum.z + 1e-16f) + acc.w / (ssum.w + 1e-16f)) + bias[lane];
    out[n * CC + lane] = val;
}

// ---------------- BN statistics: stats[0:64]=sum, stats[64:128]=sumsq --------------
__global__ __launch_bounds__(256) void bnstat_kernel(const float* __restrict__ x,
        float* __restrict__ stats) {
    int t = threadIdx.x;
    int ch = t & 63, slice = t >> 6;
    float s = 0.f, q = 0.f;
    for (int n = blockIdx.x * 4 + slice; n < NN; n += gridDim.x * 4) {
        float v = x[n * CC + ch];
        s += v; q += v * v;
    }
    __shared__ float ls[4][64], lq[4][64];
    ls[slice][ch] = s; lq[slice][ch] = q;
    __syncthreads();
    if (slice == 0) {
        s = ls[0][ch] + ls[1][ch] + ls[2][ch] + ls[3][ch];
        q = lq[0][ch] + lq[1][ch] + lq[2][ch] + lq[3][ch];
        atomicAdd(&stats[ch], s);
        atomicAdd(&stats[CC + ch], q);
    }
}

__global__ __launch_bounds__(256) void bnapply1_kernel(const float* __restrict__ gout,
        const float* __restrict__ stats, const float* __restrict__ g,
        const float* __restrict__ be, const float* __restrict__ skip,
        const float* __restrict__ bskip, float* __restrict__ outm) {
    int i = blockIdx.x * 256 + threadIdx.x;
    if (i >= NN * CC) return;
    int ch = i & 63;
    float mu  = stats[ch] * (1.f / NN);
    float var = stats[CC + ch] * (1.f / NN) - mu * mu;
    float inv = rsqrtf(var + BN_EPS);
    float v = (gout[i] - mu) * inv * g[ch] + be[ch] + skip[i] + bskip[ch];
    outm[i] = gelu_exact(v);
}

__global__ __launch_bounds__(256) void bnapply2_kernel(const float* __restrict__ gout,
        const float* __restrict__ stats, const float* __restrict__ g,
        const float* __restrict__ be, const float* __restrict__ resid,
        float* __restrict__ outm) {
    int i = blockIdx.x * 256 + threadIdx.x;
    if (i >= NN * CC) return;
    int ch = i & 63;
    float mu  = stats[ch] * (1.f / NN);
    float var = stats[CC + ch] * (1.f / NN) - mu * mu;
    float inv = rsqrtf(var + BN_EPS);
    float v = (gout[i] - mu) * inv * g[ch] + be[ch] + resid[i];
    outm[i] = gelu_exact(v);
}

// ---------------- pooling ----------------
__global__ __launch_bounds__(1024) void pool_kernel(const float* __restrict__ h2,
        const int* __restrict__ gstart, float* __restrict__ out) {
    __shared__ float4 sdata[64][17];
    int g = blockIdx.x;
    int t = threadIdx.x;
    int c4 = t & 15;
    int slice = t >> 4;
    int start = gstart[g], end = gstart[g + 1];
    float4 acc = make_float4(0.f, 0.f, 0.f, 0.f);
    for (int n = start + slice; n < end; n += 64) {
        float4 v = *(const float4*)&h2[(size_t)n * CC + c4 * 4];
        acc.x += v.x; acc.y += v.y; acc.z += v.z; acc.w += v.w;
    }
    sdata[slice][c4] = acc;
    __syncthreads();
    #pragma unroll
    for (int s = 32; s >= 1; s >>= 1) {
        if (slice < s) {
            float4 o = sdata[slice + s][c4];
            acc.x += o.x; acc.y += o.y; acc.z += o.z; acc.w += o.w;
            sdata[slice][c4] = acc;
        }
        __syncthreads();
    }
    if (slice == 0) {
        int cnt = end - start;
        float inv = 1.f / (float)((cnt > 0) ? cnt : 1);
        *(float4*)&out[g * CC + c4 * 4] =
            make_float4(acc.x * inv, acc.y * inv, acc.z * inv, acc.w * inv);
    }
}

extern "C" void kernel_launch(void* const* d_in, const int* in_sizes, int n_in,
                              void* d_out, int out_size, void* d_ws, size_t ws_size,
                              hipStream_t stream) {
    const float* x      = (const float*)d_in[0];
    const float* W1     = (const float*)d_in[1];
    const float* a_src1 = (const float*)d_in[2];
    const float* a_dst1 = (const float*)d_in[3];
    const float* b1     = (const float*)d_in[4];
    const float* Wskip  = (const float*)d_in[5];
    const float* bskip  = (const float*)d_in[6];
    const float* g1     = (const float*)d_in[7];
    const float* be1    = (const float*)d_in[8];
    const float* W2     = (const float*)d_in[9];
    const float* a_src2 = (const float*)d_in[10];
    const float* a_dst2 = (const float*)d_in[11];
    const float* b2     = (const float*)d_in[12];
    const float* g2     = (const float*)d_in[13];
    const float* be2    = (const float*)d_in[14];
    const int*   ei     = (const int*)d_in[15];
    const int*   bidx   = (const int*)d_in[16];
    float* out = (float*)d_out;

    char* w = (char*)d_ws;
    size_t o = 0;
    auto alloc = [&](size_t bytes) -> void* {
        void* p = w + o;
        o = (o + bytes + 255) & ~(size_t)255;
        return p;
    };

    unsigned short* h4b = (unsigned short*)alloc((size_t)NN * HC * 2);  // bf16 [N][C][H]
    float4* es4 = (float4*)alloc((size_t)NN * 16);
    float4* ed4 = (float4*)alloc((size_t)NN * 16);
    float* skip = (float*)alloc((size_t)NN * CC * 4);
    float* gout = (float*)alloc((size_t)NN * CC * 4);
    float* hmid = (float*)alloc((size_t)NN * CC * 4);
    float* h2   = (float*)alloc((size_t)NN * CC * 4);
    float* Bcat1 = (float*)alloc((size_t)FIN * S1 * 4);
    float* Bcat2 = (float*)alloc((size_t)CC * S2 * 4);
    int* off    = (int*)alloc((size_t)(NN + 1) * 4);
    int* csr    = (int*)alloc((size_t)ETOT * 4);
    int* gstart = (int*)alloc((size_t)(GG + 1) * 4);
    int* part   = (int*)alloc(128 * 4);
    // ---- zero region (contiguous) ----
    char* zbase = w + o;
    int* deg    = (int*)alloc((size_t)NN * 4);
    int* cursor = (int*)alloc((size_t)NN * 4);
    float* stats1 = (float*)alloc(128 * 4);
    float* stats2 = (float*)alloc(128 * 4);
    size_t zbytes = (size_t)((w + o) - zbase);

    hipMemsetAsync(zbase, 0, zbytes, stream);

    int ebk = (ETOT + 255) / 256;   // 1329
    int nbk = (NN + 255) / 256;     // 79
    int nodeblk = (NN + 3) / 4;

    // ---- pre: gbound | Bcat1 | Bcat2 | count ----
    pre1_kernel<<<79 + 192 + 80 + ebk, 256, 0, stream>>>(bidx, gstart,
            W1, Wskip, W2, a_src1, a_dst1, a_src2, a_dst2, Bcat1, Bcat2, ei, deg);
    scan1<<<nbk, 256, 0, stream>>>(deg, off, part);
    scan23<<<nbk, 256, 0, stream>>>(off, part);
    fill_kernel<<<ebk, 256, 0, stream>>>(ei, off, cursor, csr);

    // ---- layer 1 ----
    gemm_fused<<<dim3(6, 313), 256, 0, stream>>>(x, Bcat1, NN, FIN, S1,
            h4b, skip, es4, ed4, 4, 5);
    aggr_kernel<<<nodeblk, 256, 0, stream>>>(h4b, es4, ed4, off, csr, b1, gout);
    bnstat_kernel<<<128, 256, 0, stream>>>(gout, stats1);
    bnapply1_kernel<<<(NN * CC + 255) / 256, 256, 0, stream>>>(
        gout, stats1, g1, be1, skip, bskip, hmid);

    // ---- layer 2 ----
    gemm_fused<<<dim3(5, 313), 256, 0, stream>>>(hmid, Bcat2, NN, CC, S2,
            h4b, (float*)nullptr, es4, ed4, -1, 4);
    aggr_kernel<<<nodeblk, 256, 0, stream>>>(h4b, es4, ed4, off, csr, b2, gout);
    bnstat_kernel<<<128, 256, 0, stream>>>(gout, stats2);
    bnapply2_kernel<<<(NN * CC + 255) / 256, 256, 0, stream>>>(
        gout, stats2, g2, be2, hmid, h2);

    // ---- pool ----
    pool_kernel<<<GG, 1024, 0, stream>>>(h2, gstart, out);
}

// Round 10
// 254.623 us; speedup vs baseline: 3.0901x; 1.1130x over previous
//
#include <hip/hip_runtime.h>
#include <math.h>

#define NN   20000
#define EE   320000
#define ETOT 340000
#define FIN  128
#define HH   4
#define CC   64
#define HC   256
#define GG   64
#define BN_EPS 1e-5f
#define S1   384   // BcatT1 cols: 256 (W1 perm) + 64 (Wskip) + 8 (es/ed) + 56 pad
#define S2   320   // BcatT2 cols: 256 (W2 perm) + 8 (es/ed) + 56 pad

typedef _Float16 v8h __attribute__((ext_vector_type(8)));
typedef float    v4f __attribute__((ext_vector_type(4)));

__device__ __forceinline__ unsigned short f2bf(float f) {
    unsigned u = __float_as_uint(f);
    unsigned r = (u + 0x7FFF + ((u >> 16) & 1)) >> 16;   // RNE
    return (unsigned short)r;
}
__device__ __forceinline__ float bf2f(unsigned short u) {
    return __uint_as_float((unsigned)u << 16);
}
__device__ __forceinline__ float gelu_exact(float v) {
    return 0.5f * v * (1.f + erff(v * 0.70710678118654752f));
}

// ====== pre1: gbound | BcatT1 (fp16,col-major) | BcatT2 | degree count + epos =====
// blocks [0,79): gbound; [79,271): BcatT1; [271,351): BcatT2; [351,1680): count.
__global__ __launch_bounds__(256) void pre1_kernel(
        const int* __restrict__ bidx, int* __restrict__ gstart,
        const float* __restrict__ W1, const float* __restrict__ Wskip,
        const float* __restrict__ W2,
        const float* __restrict__ as1, const float* __restrict__ ad1,
        const float* __restrict__ as2, const float* __restrict__ ad2,
        _Float16* __restrict__ BT1, _Float16* __restrict__ BT2,
        const int* __restrict__ ei, int* __restrict__ deg, int* __restrict__ epos) {
    int b = blockIdx.x, t = threadIdx.x;
    if (b < 79) {
        int i = b * 256 + t;
        if (i >= NN) return;
        int cur = bidx[i];
        if (i == 0) { for (int g = 0; g <= cur; ++g) gstart[g] = 0; }
        else { int prev = bidx[i - 1]; for (int g = prev + 1; g <= cur; ++g) gstart[g] = i; }
        if (i == NN - 1) { for (int g = cur + 1; g <= GG; ++g) gstart[g] = NN; }
    } else if (b < 271) {
        int i = (b - 79) * 256 + t;          // i < S1*FIN = 49152; BT1[col][k]
        int col = i >> 7, k = i & 127;
        float v;
        if (col < 256) {
            v = W1[k * 256 + (col & 3) * 64 + (col >> 2)];
        } else if (col < 320) {
            v = Wskip[k * 64 + (col - 256)];
        } else if (col < 328) {
            int kk = col - 320, h = kk & 3;
            const float* av = (kk < 4 ? as1 : ad1) + h * 64;
            const float* wr = W1 + k * 256 + h * 64;
            float s = 0.f;
            #pragma unroll 8
            for (int c = 0; c < 64; ++c) s += wr[c] * av[c];
            v = s;
        } else v = 0.f;
        BT1[i] = (_Float16)v;
    } else if (b < 351) {
        int i = (b - 271) * 256 + t;         // i < S2*CC = 20480; BT2[col][k]
        int col = i >> 6, k = i & 63;
        float v;
        if (col < 256) {
            v = W2[k * 256 + (col & 3) * 64 + (col >> 2)];
        } else if (col < 264) {
            int kk = col - 256, h = kk & 3;
            const float* av = (kk < 4 ? as2 : ad2) + h * 64;
            const float* wr = W2 + k * 256 + h * 64;
            float s = 0.f;
            #pragma unroll 8
            for (int c = 0; c < 64; ++c) s += wr[c] * av[c];
            v = s;
        } else v = 0.f;
        BT2[i] = (_Float16)v;
    } else {
        int i = (b - 351) * 256 + t;
        if (i >= ETOT) return;
        int d = (i < EE) ? ei[EE + i] : (i - EE);
        epos[i] = atomicAdd(&deg[d], 1);
    }
}

// ---------------- single-block exclusive scan of deg -> off ------------------------
__global__ __launch_bounds__(1024) void scan_one(const int* __restrict__ deg,
        int* __restrict__ off) {
    const int PT = 20;   // 1024*20 = 20480 >= NN
    __shared__ int bs[1024];
    int t = threadIdx.x;
    int base = t * PT;
    int loc[PT];
    int sum = 0;
    #pragma unroll
    for (int j = 0; j < PT; ++j) {
        int i = base + j;
        int v = (i < NN) ? deg[i] : 0;
        sum += v; loc[j] = sum;
    }
    bs[t] = sum; __syncthreads();
    for (int s = 1; s < 1024; s <<= 1) {
        int x = (t >= s) ? bs[t - s] : 0;
        __syncthreads(); bs[t] += x; __syncthreads();
    }
    int prefix = (t == 0) ? 0 : bs[t - 1];
    #pragma unroll
    for (int j = 0; j < PT; ++j) {
        int i = base + j;
        if (i < NN) off[i] = prefix + ((j == 0) ? 0 : loc[j - 1]);
    }
    if (t == 0) off[NN] = ETOT;
}

// ---------------- CSR fill (no atomics: position precomputed) ----------------------
__global__ void fill_kernel(const int* __restrict__ ei, const int* __restrict__ off,
        const int* __restrict__ epos, int* __restrict__ csr_src) {
    int i = blockIdx.x * 256 + threadIdx.x;
    if (i >= ETOT) return;
    int s, d;
    if (i < EE) { s = ei[i]; d = ei[EE + i]; } else { s = i - EE; d = i - EE; }
    csr_src[off[d] + epos[i]] = s;
}

// ====== fused MFMA fp16 GEMM: h4b (bf16) + optional skip (fp32) + es/ed ===========
// C[M,S] = A[M,K](fp32->fp16) @ BT[S,K](fp16, col-major). Tiles of 64 cols:
// tiles 0..3 -> h4b; skip_tile -> fp32 skip; esed_tile local cols 0..7 -> es/ed.
__global__ __launch_bounds__(256) void gemm_mfma(const float* __restrict__ A,
        const _Float16* __restrict__ BT, int M, int K,
        unsigned short* __restrict__ h4b, float* __restrict__ skipO,
        float* __restrict__ esf, float* __restrict__ edf,
        int skip_tile, int esed_tile) {
    __shared__ _Float16 sA[64][40];    // [row][k], stride 80B (16B-aligned rows)
    __shared__ _Float16 sBT[64][40];   // [col][k]
    int t = threadIdx.x;
    int tile = blockIdx.x;
    int col0 = tile * 64;
    int row0 = blockIdx.y * 64;
    int wave = t >> 6, lane = t & 63;
    int l15 = lane & 15, quad = lane >> 4;
    v4f acc[4] = {};
    for (int k0 = 0; k0 < K; k0 += 32) {
        // stage A: 64 rows x 32 k, fp32 -> fp16
        {
            int r = t >> 2, c8 = t & 3;
            int gr = row0 + r;
            float4 v0 = make_float4(0.f, 0.f, 0.f, 0.f);
            float4 v1 = make_float4(0.f, 0.f, 0.f, 0.f);
            if (gr < M) {
                v0 = *(const float4*)&A[(size_t)gr * K + k0 + c8 * 8];
                v1 = *(const float4*)&A[(size_t)gr * K + k0 + c8 * 8 + 4];
            }
            v8h hv;
            hv[0] = (_Float16)v0.x; hv[1] = (_Float16)v0.y;
            hv[2] = (_Float16)v0.z; hv[3] = (_Float16)v0.w;
            hv[4] = (_Float16)v1.x; hv[5] = (_Float16)v1.y;
            hv[6] = (_Float16)v1.z; hv[7] = (_Float16)v1.w;
            *(v8h*)&sA[r][c8 * 8] = hv;
        }
        // stage BT: 64 cols x 32 k (already fp16, contiguous in k)
        {
            int c = t >> 2, seg = t & 3;
            v8h v = *(const v8h*)&BT[(size_t)(col0 + c) * K + k0 + seg * 8];
            *(v8h*)&sBT[c][seg * 8] = v;
        }
        __syncthreads();
        v8h af = *(const v8h*)&sA[wave * 16 + l15][quad * 8];
        #pragma unroll
        for (int ct = 0; ct < 4; ++ct) {
            v8h bf = *(const v8h*)&sBT[ct * 16 + l15][quad * 8];
            acc[ct] = __builtin_amdgcn_mfma_f32_16x16x32_f16(af, bf, acc[ct], 0, 0, 0);
        }
        __syncthreads();
    }
    // epilogue: lane holds D[row=quad*4+reg][col=l15] of each 16x16 subtile
    if (tile < 4) {
        #pragma unroll
        for (int ct = 0; ct < 4; ++ct) {
            #pragma unroll
            for (int reg = 0; reg < 4; ++reg) {
                int gr = row0 + wave * 16 + quad * 4 + reg;
                if (gr < M)
                    h4b[(size_t)gr * HC + col0 + ct * 16 + l15] = f2bf(acc[ct][reg]);
            }
        }
    } else if (tile == skip_tile) {
        #pragma unroll
        for (int ct = 0; ct < 4; ++ct) {
            #pragma unroll
            for (int reg = 0; reg < 4; ++reg) {
                int gr = row0 + wave * 16 + quad * 4 + reg;
                if (gr < M)
                    skipO[(size_t)gr * CC + ct * 16 + l15] = acc[ct][reg];
            }
        }
    } else if (tile == esed_tile) {
        if (l15 < 8) {   // ct==0 subtile only: local cols 0..7
            #pragma unroll
            for (int reg = 0; reg < 4; ++reg) {
                int gr = row0 + wave * 16 + quad * 4 + reg;
                if (gr < M) {
                    if (l15 < 4) esf[gr * 4 + l15] = acc[0][reg];
                    else         edf[gr * 4 + (l15 - 4)] = acc[0][reg];
                }
            }
        }
    }
}

// ================= per-destination GAT aggregation (bf16 gather) ===================
__device__ __forceinline__ void edge_acc(const float4 esv, const ushort4 hv,
        const float4 edn, float4& acc, float4& ssum) {
    float e0 = esv.x + edn.x; e0 = fmaxf(e0, 0.2f * e0); float w0 = __expf(e0);
    float e1 = esv.y + edn.y; e1 = fmaxf(e1, 0.2f * e1); float w1 = __expf(e1);
    float e2 = esv.z + edn.z; e2 = fmaxf(e2, 0.2f * e2); float w2 = __expf(e2);
    float e3 = esv.w + edn.w; e3 = fmaxf(e3, 0.2f * e3); float w3 = __expf(e3);
    acc.x += w0 * bf2f(hv.x); ssum.x += w0;
    acc.y += w1 * bf2f(hv.y); ssum.y += w1;
    acc.z += w2 * bf2f(hv.z); ssum.z += w2;
    acc.w += w3 * bf2f(hv.w); ssum.w += w3;
}

__global__ __launch_bounds__(256) void aggr_kernel(const unsigned short* __restrict__ h4b,
        const float4* __restrict__ es4, const float4* __restrict__ ed4,
        const int* __restrict__ off, const int* __restrict__ csr_src,
        const float* __restrict__ bias, float* __restrict__ out) {
    int n = blockIdx.x * 4 + (threadIdx.x >> 6);
    if (n >= NN) return;
    int lane = threadIdx.x & 63;
    float4 edn = ed4[n];
    float4 acc = make_float4(0.f, 0.f, 0.f, 0.f);
    float4 ssum = make_float4(0.f, 0.f, 0.f, 0.f);
    int beg = off[n], end = off[n + 1];
    int j = beg;
    for (; j + 4 <= end; j += 4) {
        int s0 = csr_src[j + 0];
        int s1 = csr_src[j + 1];
        int s2 = csr_src[j + 2];
        int s3 = csr_src[j + 3];
        float4 E0 = es4[s0];
        float4 E1 = es4[s1];
        float4 E2 = es4[s2];
        float4 E3 = es4[s3];
        ushort4 v0 = *(const ushort4*)&h4b[(size_t)s0 * HC + lane * 4];
        ushort4 v1 = *(const ushort4*)&h4b[(size_t)s1 * HC + lane * 4];
        ushort4 v2 = *(const ushort4*)&h4b[(size_t)s2 * HC + lane * 4];
        ushort4 v3 = *(const ushort4*)&h4b[(size_t)s3 * HC + lane * 4];
        edge_acc(E0, v0, edn, acc, ssum);
        edge_acc(E1, v1, edn, acc, ssum);
        edge_acc(E2, v2, edn, acc, ssum);
        edge_acc(E3, v3, edn, acc, ssum);
    }
    for (; j < end; ++j) {
        int s = csr_src[j];
        float4 E = es4[s];
        ushort4 v = *(const ushort4*)&h4b[(size_t)s * HC + lane * 4];
        edge_acc(E, v, edn, acc, ssum);
    }
    float val = 0.25f * (acc.x / (ssum.x + 1e-16f) + acc.y / (ssum.y + 1e-16f) +
                         acc.z / (ssum.z + 1e-16f) + acc.w / (ssum.w + 1e-16f)) + bias[lane];
    out[n * CC + lane] = val;
}

// ---------------- BN statistics: stats[0:64]=sum, stats[64:128]=sumsq --------------
__global__ __launch_bounds__(256) void bnstat_kernel(const float* __restrict__ x,
        float* __restrict__ stats) {
    int t = threadIdx.x;
    int ch = t & 63, slice = t >> 6;
    float s = 0.f, q = 0.f;
    for (int n = blockIdx.x * 4 + slice; n < NN; n += gridDim.x * 4) {
        float v = x[n * CC + ch];
        s += v; q += v * v;
    }
    __shared__ float ls[4][64], lq[4][64];
    ls[slice][ch] = s; lq[slice][ch] = q;
    __syncthreads();
    if (slice == 0) {
        s = ls[0][ch] + ls[1][ch] + ls[2][ch] + ls[3][ch];
        q = lq[0][ch] + lq[1][ch] + lq[2][ch] + lq[3][ch];
        atomicAdd(&stats[ch], s);
        atomicAdd(&stats[CC + ch], q);
    }
}

__global__ __launch_bounds__(256) void bnapply1_kernel(const float* __restrict__ gout,
        const float* __restrict__ stats, const float* __restrict__ g,
        const float* __restrict__ be, const float* __restrict__ skip,
        const float* __restrict__ bskip, float* __restrict__ outm) {
    int i = blockIdx.x * 256 + threadIdx.x;
    if (i >= NN * CC) return;
    int ch = i & 63;
    float mu  = stats[ch] * (1.f / NN);
    float var = stats[CC + ch] * (1.f / NN) - mu * mu;
    float inv = rsqrtf(var + BN_EPS);
    float v = (gout[i] - mu) * inv * g[ch] + be[ch] + skip[i] + bskip[ch];
    outm[i] = gelu_exact(v);
}

__global__ __launch_bounds__(256) void bnapply2_kernel(const float* __restrict__ gout,
        const float* __restrict__ stats, const float* __restrict__ g,
        const float* __restrict__ be, const float* __restrict__ resid,
        float* __restrict__ outm) {
    int i = blockIdx.x * 256 + threadIdx.x;
    if (i >= NN * CC) return;
    int ch = i & 63;
    float mu  = stats[ch] * (1.f / NN);
    float var = stats[CC + ch] * (1.f / NN) - mu * mu;
    float inv = rsqrtf(var + BN_EPS);
    float v = (gout[i] - mu) * inv * g[ch] + be[ch] + resid[i];
    outm[i] = gelu_exact(v);
}

// ---------------- pooling ----------------
__global__ __launch_bounds__(1024) void pool_kernel(const float* __restrict__ h2,
        const int* __restrict__ gstart, float* __restrict__ out) {
    __shared__ float4 sdata[64][17];
    int g = blockIdx.x;
    int t = threadIdx.x;
    int c4 = t & 15;
    int slice = t >> 4;
    int start = gstart[g], end = gstart[g + 1];
    float4 acc = make_float4(0.f, 0.f, 0.f, 0.f);
    for (int n = start + slice; n < end; n += 64) {
        float4 v = *(const float4*)&h2[(size_t)n * CC + c4 * 4];
        acc.x += v.x; acc.y += v.y; acc.z += v.z; acc.w += v.w;
    }
    sdata[slice][c4] = acc;
    __syncthreads();
    #pragma unroll
    for (int s = 32; s >= 1; s >>= 1) {
        if (slice < s) {
            float4 o = sdata[slice + s][c4];
            acc.x += o.x; acc.y += o.y; acc.z += o.z; acc.w += o.w;
            sdata[slice][c4] = acc;
        }
        __syncthreads();
    }
    if (slice == 0) {
        int cnt = end - start;
        float inv = 1.f / (float)((cnt > 0) ? cnt : 1);
        *(float4*)&out[g * CC + c4 * 4] =
            make_float4(acc.x * inv, acc.y * inv, acc.z * inv, acc.w * inv);
    }
}

extern "C" void kernel_launch(void* const* d_in, const int* in_sizes, int n_in,
                              void* d_out, int out_size, void* d_ws, size_t ws_size,
                              hipStream_t stream) {
    const float* x      = (const float*)d_in[0];
    const float* W1     = (const float*)d_in[1];
    const float* a_src1 = (const float*)d_in[2];
    const float* a_dst1 = (const float*)d_in[3];
    const float* b1     = (const float*)d_in[4];
    const float* Wskip  = (const float*)d_in[5];
    const float* bskip  = (const float*)d_in[6];
    const float* g1     = (const float*)d_in[7];
    const float* be1    = (const float*)d_in[8];
    const float* W2     = (const float*)d_in[9];
    const float* a_src2 = (const float*)d_in[10];
    const float* a_dst2 = (const float*)d_in[11];
    const float* b2     = (const float*)d_in[12];
    const float* g2     = (const float*)d_in[13];
    const float* be2    = (const float*)d_in[14];
    const int*   ei     = (const int*)d_in[15];
    const int*   bidx   = (const int*)d_in[16];
    float* out = (float*)d_out;

    char* w = (char*)d_ws;
    size_t o = 0;
    auto alloc = [&](size_t bytes) -> void* {
        void* p = w + o;
        o = (o + bytes + 255) & ~(size_t)255;
        return p;
    };

    unsigned short* h4b = (unsigned short*)alloc((size_t)NN * HC * 2);  // bf16 [N][C][H]
    float4* es4 = (float4*)alloc((size_t)NN * 16);
    float4* ed4 = (float4*)alloc((size_t)NN * 16);
    float* skip = (float*)alloc((size_t)NN * CC * 4);
    float* gout = (float*)alloc((size_t)NN * CC * 4);
    float* hmid = (float*)alloc((size_t)NN * CC * 4);
    float* h2   = (float*)alloc((size_t)NN * CC * 4);
    _Float16* BT1 = (_Float16*)alloc((size_t)S1 * FIN * 2);
    _Float16* BT2 = (_Float16*)alloc((size_t)S2 * CC * 2);
    int* off    = (int*)alloc((size_t)(NN + 1) * 4);
    int* csr    = (int*)alloc((size_t)ETOT * 4);
    int* epos   = (int*)alloc((size_t)ETOT * 4);
    int* gstart = (int*)alloc((size_t)(GG + 1) * 4);
    // ---- zero region (contiguous) ----
    char* zbase = w + o;
    int* deg    = (int*)alloc((size_t)NN * 4);
    float* stats1 = (float*)alloc(128 * 4);
    float* stats2 = (float*)alloc(128 * 4);
    size_t zbytes = (size_t)((w + o) - zbase);

    hipMemsetAsync(zbase, 0, zbytes, stream);

    int ebk = (ETOT + 255) / 256;   // 1329
    int nodeblk = (NN + 3) / 4;

    // ---- pre: gbound | BcatT1 | BcatT2 | count+epos ----
    pre1_kernel<<<79 + 192 + 80 + ebk, 256, 0, stream>>>(bidx, gstart,
            W1, Wskip, W2, a_src1, a_dst1, a_src2, a_dst2, BT1, BT2, ei, deg, epos);
    scan_one<<<1, 1024, 0, stream>>>(deg, off);
    fill_kernel<<<ebk, 256, 0, stream>>>(ei, off, epos, csr);

    // ---- layer 1 ----
    gemm_mfma<<<dim3(6, 313), 256, 0, stream>>>(x, BT1, NN, FIN,
            h4b, skip, (float*)es4, (float*)ed4, 4, 5);
    aggr_kernel<<<nodeblk, 256, 0, stream>>>(h4b, es4, ed4, off, csr, b1, gout);
    bnstat_kernel<<<128, 256, 0, stream>>>(gout, stats1);
    bnapply1_kernel<<<(NN * CC + 255) / 256, 256, 0, stream>>>(
        gout, stats1, g1, be1, skip, bskip, hmid);

    // ---- layer 2 ----
    gemm_mfma<<<dim3(5, 313), 256, 0, stream>>>(hmid, BT2, NN, CC,
            h4b, (float*)nullptr, (float*)es4, (float*)ed4, -1, 4);
    aggr_kernel<<<nodeblk, 256, 0, stream>>>(h4b, es4, ed4, off, csr, b2, gout);
    bnstat_kernel<<<128, 256, 0, stream>>>(gout, stats2);
    bnapply2_kernel<<<(NN * CC + 255) / 256, 256, 0, stream>>>(
        gout, stats2, g2, be2, hmid, h2);

    // ---- pool ----
    pool_kernel<<<GG, 1024, 0, stream>>>(h2, gstart, out);
}